// Round 5
// baseline (422.848 us; speedup 1.0000x reference)
//
#include <hip/hip_runtime.h>
#include <cstddef>

// Problem dims
#define CI_  64
#define CO_  256
#define DD_  31
#define HH_  96
#define WW_  96
#define HW_  (HH_*WW_)      // 9216
#define DHW_ (DD_*HW_)      // 285696
#define EPSV 1e-5f

// Padded channels-last fp16 input: xt[cig8][pd33][ph98][pw98][ci8]
#define PD_   33
#define PH_   98
#define PW_   98
#define PHW_  9604          // 98*98
#define PDHW_ 316932        // 33*9604

// Conv tile: M=128 (8h x 16w) x N=256, one d per block. 8 waves: 2 (M) x 4 (N).
// LDS halo: [dd3][row10][cig8][col18][ci8] halves — linear in task order.
#define S_COL 8
#define S_CIG 144           // 18*8
#define S_ROW 1152          // 8*144
#define S_DD  11520         // 10*1152
#define NTASK 4320          // 3*10*8*18 real 16B tasks
#define NTASKP 4352         // padded
#define XH_N  (NTASKP*8)    // 34816 halves = 69632 B

#define NTILE 72            // 12 hti * 6 wti per d-plane
#define NBLK  (NTILE*DD_)   // 2232 conv blocks (= 8*279, XCD-exact)
#define GSP   128           // spatial elems per block gate region per co

// prep kernel block ranges
#define PREP_RB 216         // repack: 55296 threads
#define PREP_PB 1239        // pad_zero: 316932 threads
#define PREP_TB 279         // transpose: 71424 threads
#define PREP_NB (PREP_RB + PREP_PB + PREP_TB)

typedef _Float16 half8   __attribute__((ext_vector_type(8)));
typedef _Float16 half4v  __attribute__((ext_vector_type(4)));
typedef float    float4v __attribute__((ext_vector_type(4)));

__device__ __forceinline__ void gl_lds16(const _Float16* g, _Float16* l) {
  __builtin_amdgcn_global_load_lds(
      (const __attribute__((address_space(1))) unsigned int*)(g),
      (__attribute__((address_space(3))) unsigned int*)(l), 16, 0, 0);
}

// -------- fused prep: weight repack + border zero + interior transpose --------
// blocks [0,216): w[co][ci][27] fp32 -> wr2[t][kc][cog][quad][lw][ci8] fp16
// blocks [216,1455): zero the padded border of xt
// blocks [1455,1734): fp32 NCDHW -> fp16 channels-last interior, float4-wide
__global__ __launch_bounds__(256) void prep_k(const float* __restrict__ w,
                                              const float* __restrict__ x,
                                              _Float16* __restrict__ wr2,
                                              _Float16* __restrict__ xt) {
  const int bid = blockIdx.x;
  if (bid < PREP_RB) {
    int idx = bid * 256 + threadIdx.x;          // 27*2*16*4*16 = 55296
    int lw   = idx & 15;
    int quad = (idx >> 4) & 3;
    int cog  = (idx >> 6) & 15;
    int tkc  = idx >> 10;          // t*2+kc
    int kc   = tkc & 1;
    int t    = tkc >> 1;
    int co   = cog * 16 + lw;
    int cib  = kc * 32 + quad * 8;
    half8 v;
#pragma unroll
    for (int s = 0; s < 8; s++)
      v[s] = (_Float16)w[(size_t)co * 1728 + (size_t)(cib + s) * 27 + t];
    *(half8*)(wr2 + (size_t)idx * 8) = v;
  } else if (bid < PREP_RB + PREP_PB) {
    int p = (bid - PREP_RB) * 256 + threadIdx.x;
    if (p >= PDHW_) return;
    int pd  = p / PHW_;
    int rem = p - pd * PHW_;
    int ph  = rem / PW_;
    int pw  = rem - ph * PW_;
    bool in = (pd >= 1) & (pd <= DD_) & (ph >= 1) & (ph <= HH_) & (pw >= 1) & (pw <= WW_);
    if (in) return;
    half8 z = (half8)(_Float16)0.f;
#pragma unroll
    for (int cig = 0; cig < 8; cig++)
      *(half8*)(xt + ((size_t)cig * PDHW_ + p) * 8) = z;
  } else {
    int idx = (bid - PREP_RB - PREP_PB) * 256 + threadIdx.x;  // 31*96*24 = 71424
    if (idx >= 31 * 96 * 24) return;
    int wq  = idx % 24;
    int rem = idx / 24;
    int h   = rem % 96;
    int d   = rem / 96;
    const float* xp = x + (size_t)d * HW_ + (size_t)h * WW_ + wq * 4;
    size_t p0 = (size_t)(d + 1) * PHW_ + (size_t)(h + 1) * PW_ + (wq * 4 + 1);
#pragma unroll 1
    for (int cig = 0; cig < 8; cig++) {
      float4 vv[8];
#pragma unroll
      for (int s = 0; s < 8; s++)
        vv[s] = *(const float4*)(xp + (size_t)(cig * 8 + s) * DHW_);
#pragma unroll
      for (int k = 0; k < 4; k++) {
        half8 o;
#pragma unroll
        for (int s = 0; s < 8; s++) o[s] = (_Float16)(&vv[s].x)[k];
        *(half8*)(xt + ((size_t)cig * PDHW_ + p0 + k) * 8) = o;
      }
    }
  }
}

__device__ __forceinline__ float tanh_f(float v) {
  float t = __expf(-2.f * fabsf(v));
  return copysignf((1.f - t) * __builtin_amdgcn_rcpf(1.f + t), v);
}
__device__ __forceinline__ float sigm_f(float v) {
  return __builtin_amdgcn_rcpf(1.f + __expf(-v));
}

// -------- conv3d (implicit GEMM, f16 MFMA) + BN + act -> block-private gates ----
// grid: 2232 blocks (XCD-chunk swizzled). block 512 = 8 waves (2 M x 4 N).
// Single staging phase (global_load_lds direct), ONE barrier, barrier-free K
// loop (B reg double-buffered). Epilogue restages the wave's 64co x 64sp tile
// through (dead) halo LDS so gate stores are 128B-contiguous b128 writes.
__global__ __launch_bounds__(512, 4) void conv_mfma_k(
    const _Float16* __restrict__ xt, const _Float16* __restrict__ wr2,
    const float* __restrict__ gamma, const float* __restrict__ beta,
    const float* __restrict__ mean, const float* __restrict__ var,
    _Float16* __restrict__ gates)
{
  __shared__ _Float16 xh[XH_N];

  // XCD-chunked swizzle: 2232 = 8 * 279 exactly (bijective)
  const int bid  = blockIdx.x;
  const int flat = (bid & 7) * 279 + (bid >> 3);
  const int d    = flat / NTILE;
  const int bx   = flat - d * NTILE;
  const int wti  = bx % 6;
  const int hti  = bx / 6;
  const int h0   = hti * 8, w0 = wti * 16;

  const int tid  = threadIdx.x;
  const int lane = tid & 63;
  const int wave = __builtin_amdgcn_readfirstlane(tid >> 6);
  const int wm   = wave >> 2;        // M half (0,1)
  const int wn   = wave & 3;         // co group (64 each)
  const int lw   = lane & 15;        // A: m(spatial w)  B: n(co)
  const int quad = lane >> 4;        // k-group (8 ci)

  // ---- stage halo: 4352 16B tasks, direct global->LDS DMA, all in-bounds ----
#pragma unroll 1
  for (int it = 0; it < 9; ++it) {
    const int wb = it * 512 + wave * 64;       // wave-uniform LDS base task
    if (wb < NTASKP) {
      const int task = wb + lane;
      const int tt   = task < NTASK ? task : (NTASK - 1);  // spare lanes dup
      int col = tt % 18;
      int rc  = tt / 18;
      int cig = rc & 7;
      int dr  = rc >> 3;
      int dd  = dr / 10;
      int row = dr - dd * 10;
      const _Float16* g = xt + (((size_t)cig * PDHW_ + (size_t)(d + dd) * PHW_ +
                                 (size_t)(h0 + row) * PW_ + (w0 + col)) << 3);
      gl_lds16(g, xh + (size_t)wb * 8);
    }
  }

  float4v acc[4][4];
#pragma unroll
  for (int m = 0; m < 4; m++)
#pragma unroll
    for (int j = 0; j < 4; j++) acc[m][j] = (float4v)0.f;

  __syncthreads();   // vmcnt(0) drain of global_load_lds + barrier

  // ---- K loop: 54 steps (t9 x kc x kw), B reg-double-buffered, no barriers --
  const int abase0 = quad * S_CIG + lw * S_COL + (wm * 4) * S_ROW;

  // step s -> (t9, kc, kw): t9 = s/6, kc = (s%6)/3, kw = s%3
#define LOADB(bf, s)                                                          \
  {                                                                           \
    const int t9_ = (s) / 6, sub_ = (s) - 6 * t9_;                            \
    const int kc_ = sub_ / 3, kw_ = sub_ - 3 * kc_;                           \
    const int t_  = t9_ * 3 + kw_;                                            \
    const _Float16* bp_ =                                                     \
        wr2 + (((size_t)((t_ * 2 + kc_) * 16 + wn * 4)) << 9) + (lane << 3);  \
    bf[0] = *(const half8*)(bp_);                                             \
    bf[1] = *(const half8*)(bp_ + (1 << 9));                                  \
    bf[2] = *(const half8*)(bp_ + (2 << 9));                                  \
    bf[3] = *(const half8*)(bp_ + (3 << 9));                                  \
  }

#define STEP(s, bf)                                                           \
  {                                                                           \
    const int t9_ = (s) / 6, sub_ = (s) - 6 * t9_;                            \
    const int kc_ = sub_ / 3, kw_ = sub_ - 3 * kc_;                           \
    const int kd_ = t9_ / 3, kh_ = t9_ - 3 * kd_;                             \
    const int ab_ = abase0 + kd_ * S_DD + kh_ * S_ROW + kc_ * (4 * S_CIG) +   \
                    kw_ * S_COL;                                              \
    half8 af0 = *(const half8*)(xh + ab_);                                    \
    half8 af1 = *(const half8*)(xh + ab_ + S_ROW);                            \
    half8 af2 = *(const half8*)(xh + ab_ + 2 * S_ROW);                        \
    half8 af3 = *(const half8*)(xh + ab_ + 3 * S_ROW);                        \
    __builtin_amdgcn_s_setprio(1);                                            \
    _Pragma("unroll")                                                         \
    for (int j = 0; j < 4; ++j) {                                             \
      acc[0][j] = __builtin_amdgcn_mfma_f32_16x16x32_f16(af0, bf[j], acc[0][j], 0, 0, 0); \
      acc[1][j] = __builtin_amdgcn_mfma_f32_16x16x32_f16(af1, bf[j], acc[1][j], 0, 0, 0); \
      acc[2][j] = __builtin_amdgcn_mfma_f32_16x16x32_f16(af2, bf[j], acc[2][j], 0, 0, 0); \
      acc[3][j] = __builtin_amdgcn_mfma_f32_16x16x32_f16(af3, bf[j], acc[3][j], 0, 0, 0); \
    }                                                                         \
    __builtin_amdgcn_s_setprio(0);                                            \
  }

  half8 bfa[4], bfb[4];
  LOADB(bfa, 0)
#pragma unroll 1
  for (int i = 0; i < 27; ++i) {
    const int s0 = 2 * i;
    LOADB(bfb, s0 + 1)
    STEP(s0, bfa)
    if (i < 26) LOADB(bfa, s0 + 2)
    STEP(s0 + 1, bfb)
  }
#undef LOADB
#undef STEP

  // ---- epilogue: BN + act, LDS restage -> coalesced b128 gate stores ----
  __syncthreads();   // halo is dead; reuse xh[0..32768) as 8 x 8KB wave tiles

  _Float16* wt = xh + wave * 4096;   // [co_local 64][sp_local 64], XOR-swizzled
  const bool istanh = (wn == 0) || (wn == 3);
#pragma unroll
  for (int j = 0; j < 4; j++) {
    const int co  = wn * 64 + j * 16 + lw;
    const int col = j * 16 + lw;                 // co_local
    const float s  = gamma[co] * rsqrtf(var[co] + EPSV);
    const float bb = fmaf(-mean[co], s, beta[co]);
    const int key = (col & 7) << 3;              // sp XOR-swizzle key
#pragma unroll
    for (int m = 0; m < 4; m++) {
      half4v hv;
#pragma unroll
      for (int reg = 0; reg < 4; reg++) {
        float v = fmaf(acc[m][j][reg], s, bb);
        float a;
        if (istanh) a = tanh_f(v); else a = sigm_f(v);
        hv[reg] = (_Float16)a;
      }
      // sp_local = m*16 + quad*4 + reg
      *(half4v*)(wt + col * 64 + ((m * 16 + quad * 4) ^ key)) = hv;
    }
  }
  // wave-private region: no barrier needed between write and read
  _Float16* gb = gates + ((size_t)(d * NTILE + bx) * 256 + wn * 64) * GSP + wm * 64;
  const int rb = (lane & 7) * 8;                 // sp_local octet
#pragma unroll
  for (int s8 = 0; s8 < 8; s8++) {
    const int col = s8 * 8 + (lane >> 3);        // co_local
    half8 rv = *(const half8*)(wt + col * 64 + (rb ^ ((col & 7) << 3)));
    *(half8*)(gb + (size_t)col * GSP + rb) = rv; // 128B contiguous per 8 lanes
  }
}

// -------- SRU recurrence over d; thread per (c, bx, 4-wide sp); pipelined ----
__global__ __launch_bounds__(256) void recurrence_k(const _Float16* __restrict__ gates,
                                                    float* __restrict__ out) {
  const int idx = blockIdx.x * 256 + threadIdx.x;   // 64*72*32 = 147456
  const int q   = idx & 31;          // sp quad
  const int t2  = idx >> 5;          // c*72 + bx
  const int c   = t2 / NTILE;
  const int bx  = t2 - c * NTILE;
  const int hti = bx / 6, wti = bx - hti * 6;
  const int sp  = q * 4;
  const int h   = hti * 8 + (sp >> 4);
  const int w   = wti * 16 + (sp & 15);

  const size_t DSTR = (size_t)NTILE * 256 * GSP;    // per-d gate stride
  const _Float16* g0 = gates + (size_t)bx * 256 * GSP + sp;
  float* op = out + (size_t)c * DHW_ + (size_t)h * WW_ + w;

#define LD(dv, gate) (*(const half4v*)(g0 + (size_t)(dv) * DSTR + (size_t)(c + ((gate) << 6)) * GSP))

  // d = 0 (peeled): C = 1 - f
  half4v cf = LD(0, 1), cr = LD(0, 2), cx = LD(0, 3);
  half4v nwx = LD(1, 0), nf = LD(1, 1), nr = LD(1, 2), nx = LD(1, 3);
  float C[4];
  {
    float4 st;
#pragma unroll
    for (int k = 0; k < 4; k++) {
      C[k] = 1.f - (float)cf[k];
      float r0 = (float)cr[k], x0 = (float)cx[k];
      (&st.x)[k] = fmaf(r0, C[k] - x0, x0);
    }
    *(float4*)op = st;
  }
#pragma unroll 1
  for (int d = 1; d < DD_; d++) {
    half4v cwx = nwx; cf = nf; cr = nr; cx = nx;
    if (d < DD_ - 1) {                 // prefetch d+1 while computing d
      nwx = LD(d + 1, 0); nf = LD(d + 1, 1);
      nr  = LD(d + 1, 2); nx = LD(d + 1, 3);
    }
    float4 st;
#pragma unroll
    for (int k = 0; k < 4; k++) {
      float wx0 = (float)cwx[k], f0 = (float)cf[k], r0 = (float)cr[k], x0 = (float)cx[k];
      C[k] = fmaf(f0, C[k] - wx0, wx0);
      (&st.x)[k] = fmaf(r0, C[k] - x0, x0);
    }
    *(float4*)(op + (size_t)d * HW_) = st;
  }
#undef LD
}

extern "C" void kernel_launch(void* const* d_in, const int* in_sizes, int n_in,
                              void* d_out, int out_size, void* d_ws, size_t ws_size,
                              hipStream_t stream) {
  const float* x     = (const float*)d_in[0];
  const float* w     = (const float*)d_in[1];
  const float* gamma = (const float*)d_in[2];
  const float* beta  = (const float*)d_in[3];
  const float* mean  = (const float*)d_in[4];
  const float* var   = (const float*)d_in[5];
  float* out = (float*)d_out;

  // ws: [wr2: 884736 B][xt: 8*316932*16 = 40567296 B][gates: 31*72*256*128*2 B]
  _Float16* wr2   = (_Float16*)d_ws;
  _Float16* xt    = (_Float16*)((char*)d_ws + 884736);
  _Float16* gates = (_Float16*)((char*)d_ws + 884736 + 40567296);

  prep_k<<<PREP_NB, 256, 0, stream>>>(w, x, wr2, xt);
  conv_mfma_k<<<NBLK, 512, 0, stream>>>(xt, wr2, gamma, beta, mean, var, gates);
  recurrence_k<<<(64 * NTILE * 32) / 256, 256, 0, stream>>>(gates, out);
}

// Round 6
// 422.619 us; speedup vs baseline: 1.0005x; 1.0005x over previous
//
#include <hip/hip_runtime.h>
#include <cstddef>

// Problem dims
#define CI_  64
#define CO_  256
#define DD_  31
#define HH_  96
#define WW_  96
#define HW_  (HH_*WW_)      // 9216
#define DHW_ (DD_*HW_)      // 285696
#define EPSV 1e-5f

// Padded channels-last fp16 input: xt[cig8][pd33][ph98][pw98][ci8]
#define PD_   33
#define PH_   98
#define PW_   98
#define PHW_  9604          // 98*98
#define PDHW_ 316932        // 33*9604

// Conv tile: M=128 (8h x 16w) x N=256, one d per block. 8 waves: 2 (M) x 4 (N).
// LDS halo: [dd3][row10][cig8][col18][ci8] halves — linear in task order.
#define S_COL 8
#define S_CIG 144           // 18*8
#define S_ROW 1152          // 8*144
#define S_DD  11520         // 10*1152
#define NTASK 4320          // 3*10*8*18 real 16B tasks
#define NTASKP 4352         // padded
#define XH_N  (NTASKP*8)    // 34816 halves = 69632 B

#define NTILE 72            // 12 hti * 6 wti per d-plane
#define NBLK  (NTILE*DD_)   // 2232 conv blocks (= 8*279, XCD-exact)

// gates layout: per (d,bx) block of 32768 halves: [c 64][q 32][gate 4][spw 4]
// (sp = q*4 + spw). Recurrence reads {4 gates x 4 spw} = 32B contiguous.
#define GBLK 32768
#define GDSTR ((size_t)NTILE * GBLK)

// prep kernel block ranges
#define PREP_RB 216         // repack: 55296 threads
#define PREP_PB 1239        // pad_zero: 316932 threads
#define PREP_TB 279         // transpose: 71424 threads
#define PREP_NB (PREP_RB + PREP_PB + PREP_TB)

typedef _Float16 half8   __attribute__((ext_vector_type(8)));
typedef _Float16 half4v  __attribute__((ext_vector_type(4)));
typedef float    float4v __attribute__((ext_vector_type(4)));

__device__ __forceinline__ void gl_lds16(const _Float16* g, _Float16* l) {
  __builtin_amdgcn_global_load_lds(
      (const __attribute__((address_space(1))) unsigned int*)(g),
      (__attribute__((address_space(3))) unsigned int*)(l), 16, 0, 0);
}

// -------- fused prep: weight repack + border zero + interior transpose --------
__global__ __launch_bounds__(256) void prep_k(const float* __restrict__ w,
                                              const float* __restrict__ x,
                                              _Float16* __restrict__ wr2,
                                              _Float16* __restrict__ xt) {
  const int bid = blockIdx.x;
  if (bid < PREP_RB) {
    int idx = bid * 256 + threadIdx.x;          // 27*2*16*4*16 = 55296
    int lw   = idx & 15;
    int quad = (idx >> 4) & 3;
    int cog  = (idx >> 6) & 15;
    int tkc  = idx >> 10;          // t*2+kc
    int kc   = tkc & 1;
    int t    = tkc >> 1;
    int co   = cog * 16 + lw;
    int cib  = kc * 32 + quad * 8;
    half8 v;
#pragma unroll
    for (int s = 0; s < 8; s++)
      v[s] = (_Float16)w[(size_t)co * 1728 + (size_t)(cib + s) * 27 + t];
    *(half8*)(wr2 + (size_t)idx * 8) = v;
  } else if (bid < PREP_RB + PREP_PB) {
    int p = (bid - PREP_RB) * 256 + threadIdx.x;
    if (p >= PDHW_) return;
    int pd  = p / PHW_;
    int rem = p - pd * PHW_;
    int ph  = rem / PW_;
    int pw  = rem - ph * PW_;
    bool in = (pd >= 1) & (pd <= DD_) & (ph >= 1) & (ph <= HH_) & (pw >= 1) & (pw <= WW_);
    if (in) return;
    half8 z = (half8)(_Float16)0.f;
#pragma unroll
    for (int cig = 0; cig < 8; cig++)
      *(half8*)(xt + ((size_t)cig * PDHW_ + p) * 8) = z;
  } else {
    int idx = (bid - PREP_RB - PREP_PB) * 256 + threadIdx.x;  // 31*96*24 = 71424
    if (idx >= 31 * 96 * 24) return;
    int wq  = idx % 24;
    int rem = idx / 24;
    int h   = rem % 96;
    int d   = rem / 96;
    const float* xp = x + (size_t)d * HW_ + (size_t)h * WW_ + wq * 4;
    size_t p0 = (size_t)(d + 1) * PHW_ + (size_t)(h + 1) * PW_ + (wq * 4 + 1);
#pragma unroll 1
    for (int cig = 0; cig < 8; cig++) {
      float4 vv[8];
#pragma unroll
      for (int s = 0; s < 8; s++)
        vv[s] = *(const float4*)(xp + (size_t)(cig * 8 + s) * DHW_);
#pragma unroll
      for (int k = 0; k < 4; k++) {
        half8 o;
#pragma unroll
        for (int s = 0; s < 8; s++) o[s] = (_Float16)(&vv[s].x)[k];
        *(half8*)(xt + ((size_t)cig * PDHW_ + p0 + k) * 8) = o;
      }
    }
  }
}

__device__ __forceinline__ float tanh_f(float v) {
  float t = __expf(-2.f * fabsf(v));
  return copysignf((1.f - t) * __builtin_amdgcn_rcpf(1.f + t), v);
}
__device__ __forceinline__ float sigm_f(float v) {
  return __builtin_amdgcn_rcpf(1.f + __expf(-v));
}

// -------- conv3d (implicit GEMM, f16 MFMA) + BN + act -> interleaved gates ----
// grid: 2232 blocks (XCD-chunk swizzled). block 512 = 8 waves (2 M x 4 N).
// Single staging phase (global_load_lds direct), ONE barrier, barrier-free,
// FULLY UNROLLED 54-step K loop (all addresses compile-time immediates),
// A/B register double-buffered.
__global__ __launch_bounds__(512, 4) void conv_mfma_k(
    const _Float16* __restrict__ xt, const _Float16* __restrict__ wr2,
    const float* __restrict__ gamma, const float* __restrict__ beta,
    const float* __restrict__ mean, const float* __restrict__ var,
    _Float16* __restrict__ gates)
{
  __shared__ _Float16 xh[XH_N];

  // XCD-chunked swizzle: 2232 = 8 * 279 exactly (bijective)
  const int bid  = blockIdx.x;
  const int flat = (bid & 7) * 279 + (bid >> 3);
  const int d    = flat / NTILE;
  const int bx   = flat - d * NTILE;
  const int wti  = bx % 6;
  const int hti  = bx / 6;
  const int h0   = hti * 8, w0 = wti * 16;

  const int tid  = threadIdx.x;
  const int lane = tid & 63;
  const int wave = __builtin_amdgcn_readfirstlane(tid >> 6);
  const int wm   = wave >> 2;        // M half (0,1)
  const int wn   = wave & 3;         // co group (64 each)
  const int lw   = lane & 15;        // A: m(spatial w)  B: n(co)
  const int quad = lane >> 4;        // k-group (8 ci)

  // ---- stage halo: 4352 16B tasks, direct global->LDS DMA, all in-bounds ----
#pragma unroll 1
  for (int it = 0; it < 9; ++it) {
    const int wb = it * 512 + wave * 64;       // wave-uniform LDS base task
    if (wb < NTASKP) {
      const int task = wb + lane;
      const int tt   = task < NTASK ? task : (NTASK - 1);  // spare lanes dup
      int col = tt % 18;
      int rc  = tt / 18;
      int cig = rc & 7;
      int dr  = rc >> 3;
      int dd  = dr / 10;
      int row = dr - dd * 10;
      const _Float16* g = xt + (((size_t)cig * PDHW_ + (size_t)(d + dd) * PHW_ +
                                 (size_t)(h0 + row) * PW_ + (w0 + col)) << 3);
      gl_lds16(g, xh + (size_t)wb * 8);
    }
  }

  float4v acc[4][4];
#pragma unroll
  for (int m = 0; m < 4; m++)
#pragma unroll
    for (int j = 0; j < 4; j++) acc[m][j] = (float4v)0.f;

  __syncthreads();   // vmcnt(0) drain of global_load_lds + barrier

  // ---- K loop: 54 steps (t9 x kc x kw), fully unrolled, reg double-buffered --
  const int abase0 = quad * S_CIG + lw * S_COL + (wm * 4) * S_ROW;

  // step s -> (t9, kc, kw): t9 = s/6, kc = (s%6)/3, kw = s%3  (s compile-time)
#define LOADB(bf, s)                                                          \
  {                                                                           \
    const int t9_ = (s) / 6, sub_ = (s) - 6 * t9_;                            \
    const int kc_ = sub_ / 3, kw_ = sub_ - 3 * kc_;                           \
    const int t_  = t9_ * 3 + kw_;                                            \
    const _Float16* bp_ =                                                     \
        wr2 + (((size_t)((t_ * 2 + kc_) * 16 + wn * 4)) << 9) + (lane << 3);  \
    bf[0] = *(const half8*)(bp_);                                             \
    bf[1] = *(const half8*)(bp_ + (1 << 9));                                  \
    bf[2] = *(const half8*)(bp_ + (2 << 9));                                  \
    bf[3] = *(const half8*)(bp_ + (3 << 9));                                  \
  }

#define STEP(s, bf)                                                           \
  {                                                                           \
    const int t9_ = (s) / 6, sub_ = (s) - 6 * t9_;                            \
    const int kc_ = sub_ / 3, kw_ = sub_ - 3 * kc_;                           \
    const int kd_ = t9_ / 3, kh_ = t9_ - 3 * kd_;                             \
    const int ab_ = abase0 + kd_ * S_DD + kh_ * S_ROW + kc_ * (4 * S_CIG) +   \
                    kw_ * S_COL;                                              \
    half8 af0 = *(const half8*)(xh + ab_);                                    \
    half8 af1 = *(const half8*)(xh + ab_ + S_ROW);                            \
    half8 af2 = *(const half8*)(xh + ab_ + 2 * S_ROW);                        \
    half8 af3 = *(const half8*)(xh + ab_ + 3 * S_ROW);                        \
    __builtin_amdgcn_s_setprio(1);                                            \
    _Pragma("unroll")                                                         \
    for (int j = 0; j < 4; ++j) {                                             \
      acc[0][j] = __builtin_amdgcn_mfma_f32_16x16x32_f16(af0, bf[j], acc[0][j], 0, 0, 0); \
      acc[1][j] = __builtin_amdgcn_mfma_f32_16x16x32_f16(af1, bf[j], acc[1][j], 0, 0, 0); \
      acc[2][j] = __builtin_amdgcn_mfma_f32_16x16x32_f16(af2, bf[j], acc[2][j], 0, 0, 0); \
      acc[3][j] = __builtin_amdgcn_mfma_f32_16x16x32_f16(af3, bf[j], acc[3][j], 0, 0, 0); \
    }                                                                         \
    __builtin_amdgcn_s_setprio(0);                                            \
  }

  half8 bfa[4], bfb[4];
  LOADB(bfa, 0)
#pragma unroll
  for (int i = 0; i < 27; ++i) {
    const int s0 = 2 * i;
    LOADB(bfb, s0 + 1)
    STEP(s0, bfa)
    if (i < 26) LOADB(bfa, s0 + 2)
    STEP(s0 + 1, bfb)
  }
#undef LOADB
#undef STEP

  // ---- epilogue: BN + act, direct stores to interleaved gate layout ----
  // gates block (d*72+bx): halves [c 64][q 32][gate 4][spw 4]
  // this thread: c = j*16+lw, q = (wm*4+m)*4+quad, gate = wn, spw = reg
  _Float16* gb = gates + (size_t)(d * NTILE + bx) * GBLK + wn * 4;
  const bool istanh = (wn == 0) || (wn == 3);
#pragma unroll
  for (int j = 0; j < 4; j++) {
    const int co = wn * 64 + j * 16 + lw;
    const int c  = j * 16 + lw;
    const float s  = gamma[co] * rsqrtf(var[co] + EPSV);
    const float bb = fmaf(-mean[co], s, beta[co]);
#pragma unroll
    for (int m = 0; m < 4; m++) {
      half4v hv;
#pragma unroll
      for (int reg = 0; reg < 4; reg++) {
        float v = fmaf(acc[m][j][reg], s, bb);
        hv[reg] = (_Float16)(istanh ? tanh_f(v) : sigm_f(v));
      }
      const int q = (wm * 4 + m) * 4 + quad;
      *(half4v*)(gb + (size_t)c * 512 + q * 16) = hv;
    }
  }
}

// -------- SRU recurrence over d; thread per (c, bx, q=4sp); pipelined ----
// gates block: [c][q][gate 4][spw 4] -> per d: 2 contiguous b128 loads.
__global__ __launch_bounds__(256) void recurrence_k(const _Float16* __restrict__ gates,
                                                    float* __restrict__ out) {
  const int idx = blockIdx.x * 256 + threadIdx.x;   // 64*72*32 = 147456
  const int q   = idx & 31;          // sp quad
  const int t2  = idx >> 5;          // c*72 + bx
  const int c   = t2 / NTILE;
  const int bx  = t2 - c * NTILE;
  const int hti = bx / 6, wti = bx - hti * 6;
  const int sp  = q * 4;
  const int h   = hti * 8 + (sp >> 4);
  const int w   = wti * 16 + (sp & 15);

  const _Float16* g0 = gates + (size_t)bx * GBLK + (size_t)c * 512 + q * 16;
  float* op = out + (size_t)c * DHW_ + (size_t)h * WW_ + w;

  // lo = {wx[0..3], f[0..3]}, hi = {r[0..3], x[0..3]}
#define LDLO(dv) (*(const half8*)(g0 + (size_t)(dv) * GDSTR))
#define LDHI(dv) (*(const half8*)(g0 + (size_t)(dv) * GDSTR + 8))

  // d = 0 (peeled): C = 1 - f
  half8 clo = LDLO(0), chi = LDHI(0);
  half8 nlo = LDLO(1), nhi = LDHI(1);
  float C[4];
  {
    float4 st;
#pragma unroll
    for (int k = 0; k < 4; k++) {
      C[k] = 1.f - (float)clo[4 + k];
      float r0 = (float)chi[k], x0 = (float)chi[4 + k];
      (&st.x)[k] = fmaf(r0, C[k] - x0, x0);
    }
    *(float4*)op = st;
  }
#pragma unroll 1
  for (int d = 1; d < DD_; d++) {
    clo = nlo; chi = nhi;
    if (d < DD_ - 1) {                 // prefetch d+1 while computing d
      nlo = LDLO(d + 1); nhi = LDHI(d + 1);
    }
    float4 st;
#pragma unroll
    for (int k = 0; k < 4; k++) {
      float wx0 = (float)clo[k],     f0 = (float)clo[4 + k];
      float r0  = (float)chi[k],     x0 = (float)chi[4 + k];
      C[k] = fmaf(f0, C[k] - wx0, wx0);
      (&st.x)[k] = fmaf(r0, C[k] - x0, x0);
    }
    *(float4*)(op + (size_t)d * HW_) = st;
  }
#undef LDLO
#undef LDHI
}

extern "C" void kernel_launch(void* const* d_in, const int* in_sizes, int n_in,
                              void* d_out, int out_size, void* d_ws, size_t ws_size,
                              hipStream_t stream) {
  const float* x     = (const float*)d_in[0];
  const float* w     = (const float*)d_in[1];
  const float* gamma = (const float*)d_in[2];
  const float* beta  = (const float*)d_in[3];
  const float* mean  = (const float*)d_in[4];
  const float* var   = (const float*)d_in[5];
  float* out = (float*)d_out;

  // ws: [wr2: 884736 B][xt: 8*316932*16 = 40567296 B][gates: 2232*65536 B]
  _Float16* wr2   = (_Float16*)d_ws;
  _Float16* xt    = (_Float16*)((char*)d_ws + 884736);
  _Float16* gates = (_Float16*)((char*)d_ws + 884736 + 40567296);

  prep_k<<<PREP_NB, 256, 0, stream>>>(w, x, wr2, xt);
  conv_mfma_k<<<NBLK, 512, 0, stream>>>(xt, wr2, gamma, beta, mean, var, gates);
  recurrence_k<<<(64 * NTILE * 32) / 256, 256, 0, stream>>>(gates, out);
}

// Round 7
// 412.618 us; speedup vs baseline: 1.0248x; 1.0242x over previous
//
#include <hip/hip_runtime.h>
#include <cstddef>

// Problem dims
#define CI_  64
#define CO_  256
#define DD_  31
#define HH_  96
#define WW_  96
#define HW_  (HH_*WW_)      // 9216
#define DHW_ (DD_*HW_)      // 285696
#define EPSV 1e-5f

// Padded channels-last fp16 input: xt[cig8][pd33][ph98][pw98][ci8]
#define PD_   33
#define PH_   98
#define PW_   98
#define PHW_  9604          // 98*98
#define PDHW_ 316932        // 33*9604

// Conv tile: M=128 (8h x 16w) x N=256, one d per block. 8 waves: 2 (M) x 4 (N).
// LDS halo: [dd3][row10][cig8][col18][ci8] halves — linear in task order.
#define S_COL 8
#define S_CIG 144           // 18*8
#define S_ROW 1152          // 8*144
#define S_DD  11520         // 10*1152
#define NTASK 4320          // 3*10*8*18 real 16B tasks
#define NTASKP 4352         // padded
#define XH_N  (NTASKP*8)    // 34816 halves = 69632 B

#define NTILE 72            // 12 hti * 6 wti per d-plane
#define NBLK  (NTILE*DD_)   // 2232 conv blocks (= 8*279, XCD-exact)

// gates layout: per (d,bx) block of 32768 halves: [c 64][q 32][gate 4][spw 4]
// (sp = q*4 + spw). Recurrence reads {4 gates x 4 spw} = 32B contiguous.
#define GBLK 32768
#define GDSTR ((size_t)NTILE * GBLK)

// prep kernel block ranges
#define PREP_RB 216         // repack: 55296 threads
#define PREP_PB 1239        // pad_zero: 316932 threads
#define PREP_TB 279         // transpose: 71424 threads
#define PREP_NB (PREP_RB + PREP_PB + PREP_TB)

typedef _Float16 half8   __attribute__((ext_vector_type(8)));
typedef _Float16 half4v  __attribute__((ext_vector_type(4)));
typedef float    float4v __attribute__((ext_vector_type(4)));

__device__ __forceinline__ void gl_lds16(const _Float16* g, _Float16* l) {
  __builtin_amdgcn_global_load_lds(
      (const __attribute__((address_space(1))) unsigned int*)(g),
      (__attribute__((address_space(3))) unsigned int*)(l), 16, 0, 0);
}

// -------- fused prep: weight repack + border zero + interior transpose --------
__global__ __launch_bounds__(256) void prep_k(const float* __restrict__ w,
                                              const float* __restrict__ x,
                                              _Float16* __restrict__ wr2,
                                              _Float16* __restrict__ xt) {
  const int bid = blockIdx.x;
  if (bid < PREP_RB) {
    int idx = bid * 256 + threadIdx.x;          // 27*2*16*4*16 = 55296
    int lw   = idx & 15;
    int quad = (idx >> 4) & 3;
    int cog  = (idx >> 6) & 15;
    int tkc  = idx >> 10;          // t*2+kc
    int kc   = tkc & 1;
    int t    = tkc >> 1;
    int co   = cog * 16 + lw;
    int cib  = kc * 32 + quad * 8;
    half8 v;
#pragma unroll
    for (int s = 0; s < 8; s++)
      v[s] = (_Float16)w[(size_t)co * 1728 + (size_t)(cib + s) * 27 + t];
    *(half8*)(wr2 + (size_t)idx * 8) = v;
  } else if (bid < PREP_RB + PREP_PB) {
    int p = (bid - PREP_RB) * 256 + threadIdx.x;
    if (p >= PDHW_) return;
    int pd  = p / PHW_;
    int rem = p - pd * PHW_;
    int ph  = rem / PW_;
    int pw  = rem - ph * PW_;
    bool in = (pd >= 1) & (pd <= DD_) & (ph >= 1) & (ph <= HH_) & (pw >= 1) & (pw <= WW_);
    if (in) return;
    half8 z = (half8)(_Float16)0.f;
#pragma unroll
    for (int cig = 0; cig < 8; cig++)
      *(half8*)(xt + ((size_t)cig * PDHW_ + p) * 8) = z;
  } else {
    int idx = (bid - PREP_RB - PREP_PB) * 256 + threadIdx.x;  // 31*96*24 = 71424
    if (idx >= 31 * 96 * 24) return;
    int wq  = idx % 24;
    int rem = idx / 24;
    int h   = rem % 96;
    int d   = rem / 96;
    const float* xp = x + (size_t)d * HW_ + (size_t)h * WW_ + wq * 4;
    size_t p0 = (size_t)(d + 1) * PHW_ + (size_t)(h + 1) * PW_ + (wq * 4 + 1);
#pragma unroll 1
    for (int cig = 0; cig < 8; cig++) {
      float4 vv[8];
#pragma unroll
      for (int s = 0; s < 8; s++)
        vv[s] = *(const float4*)(xp + (size_t)(cig * 8 + s) * DHW_);
#pragma unroll
      for (int k = 0; k < 4; k++) {
        half8 o;
#pragma unroll
        for (int s = 0; s < 8; s++) o[s] = (_Float16)(&vv[s].x)[k];
        *(half8*)(xt + ((size_t)cig * PDHW_ + p0 + k) * 8) = o;
      }
    }
  }
}

__device__ __forceinline__ float tanh_f(float v) {
  float t = __expf(-2.f * fabsf(v));
  return copysignf((1.f - t) * __builtin_amdgcn_rcpf(1.f + t), v);
}
__device__ __forceinline__ float sigm_f(float v) {
  return __builtin_amdgcn_rcpf(1.f + __expf(-v));
}

// -------- conv3d (implicit GEMM, f16 MFMA) + BN + act -> interleaved gates ----
// grid: 2232 blocks (XCD-chunk swizzled). block 512 = 8 waves (2 M x 4 N).
// Single staging phase (global_load_lds direct), ONE barrier, barrier-free K
// loop restructured into 18 groups (kd x kc x kw): the 3 kh taps share LDS
// rows with the 4 m row-blocks, so 6 ds_read_b128 feed 48 MFMA per group
// (A-LDS reads HALVED vs the per-tap loop).
__global__ __launch_bounds__(512, 4) void conv_mfma_k(
    const _Float16* __restrict__ xt, const _Float16* __restrict__ wr2,
    const float* __restrict__ gamma, const float* __restrict__ beta,
    const float* __restrict__ mean, const float* __restrict__ var,
    _Float16* __restrict__ gates)
{
  __shared__ _Float16 xh[XH_N];

  // XCD-chunked swizzle: 2232 = 8 * 279 exactly (bijective)
  const int bid  = blockIdx.x;
  const int flat = (bid & 7) * 279 + (bid >> 3);
  const int d    = flat / NTILE;
  const int bx   = flat - d * NTILE;
  const int wti  = bx % 6;
  const int hti  = bx / 6;
  const int h0   = hti * 8, w0 = wti * 16;

  const int tid  = threadIdx.x;
  const int lane = tid & 63;
  const int wave = __builtin_amdgcn_readfirstlane(tid >> 6);
  const int wm   = wave >> 2;        // M half (0,1)
  const int wn   = wave & 3;         // co group (64 each)
  const int lw   = lane & 15;        // A: m(spatial w)  B: n(co)
  const int quad = lane >> 4;        // k-group (8 ci)

  // ---- stage halo: 4352 16B tasks, direct global->LDS DMA, all in-bounds ----
#pragma unroll 1
  for (int it = 0; it < 9; ++it) {
    const int wb = it * 512 + wave * 64;       // wave-uniform LDS base task
    if (wb < NTASKP) {
      const int task = wb + lane;
      const int tt   = task < NTASK ? task : (NTASK - 1);  // spare lanes dup
      int col = tt % 18;
      int rc  = tt / 18;
      int cig = rc & 7;
      int dr  = rc >> 3;
      int dd  = dr / 10;
      int row = dr - dd * 10;
      const _Float16* g = xt + (((size_t)cig * PDHW_ + (size_t)(d + dd) * PHW_ +
                                 (size_t)(h0 + row) * PW_ + (w0 + col)) << 3);
      gl_lds16(g, xh + (size_t)wb * 8);
    }
  }

  float4v acc[4][4];
#pragma unroll
  for (int m = 0; m < 4; m++)
#pragma unroll
    for (int j = 0; j < 4; j++) acc[m][j] = (float4v)0.f;

  __syncthreads();   // vmcnt(0) drain of global_load_lds + barrier

  // ---- K loop: 18 groups, kh-row-sharing, fully unrolled ----
  const int abase0 = quad * S_CIG + lw * S_COL + (wm * 4) * S_ROW;
  half8 af[6];
  half8 bf[4];
#pragma unroll
  for (int kd = 0; kd < 3; ++kd) {
#pragma unroll
    for (int kc = 0; kc < 2; ++kc) {
#pragma unroll
      for (int kw = 0; kw < 3; ++kw) {
        const int ab = abase0 + kd * S_DD + kc * (4 * S_CIG) + kw * S_COL;
#pragma unroll
        for (int r = 0; r < 6; ++r)
          af[r] = *(const half8*)(xh + ab + r * S_ROW);
#pragma unroll
        for (int kh = 0; kh < 3; ++kh) {
          const int t = (kd * 3 + kh) * 3 + kw;
          const _Float16* bp =
              wr2 + (((size_t)((t * 2 + kc) * 16 + wn * 4)) << 9) + (lane << 3);
#pragma unroll
          for (int j = 0; j < 4; ++j)
            bf[j] = *(const half8*)(bp + ((size_t)j << 9));
          __builtin_amdgcn_s_setprio(1);
#pragma unroll
          for (int j = 0; j < 4; ++j) {
            acc[0][j] = __builtin_amdgcn_mfma_f32_16x16x32_f16(af[kh    ], bf[j], acc[0][j], 0, 0, 0);
            acc[1][j] = __builtin_amdgcn_mfma_f32_16x16x32_f16(af[kh + 1], bf[j], acc[1][j], 0, 0, 0);
            acc[2][j] = __builtin_amdgcn_mfma_f32_16x16x32_f16(af[kh + 2], bf[j], acc[2][j], 0, 0, 0);
            acc[3][j] = __builtin_amdgcn_mfma_f32_16x16x32_f16(af[kh + 3], bf[j], acc[3][j], 0, 0, 0);
          }
          __builtin_amdgcn_s_setprio(0);
        }
      }
    }
  }

  // ---- epilogue: BN + act, direct stores to interleaved gate layout ----
  // gates block (d*72+bx): halves [c 64][q 32][gate 4][spw 4]
  // this thread: c = j*16+lw, q = (wm*4+m)*4+quad, gate = wn, spw = reg
  _Float16* gb = gates + (size_t)(d * NTILE + bx) * GBLK + wn * 4;
  const bool istanh = (wn == 0) || (wn == 3);
#pragma unroll
  for (int j = 0; j < 4; j++) {
    const int co = wn * 64 + j * 16 + lw;
    const int c  = j * 16 + lw;
    const float s  = gamma[co] * rsqrtf(var[co] + EPSV);
    const float bb = fmaf(-mean[co], s, beta[co]);
#pragma unroll
    for (int m = 0; m < 4; m++) {
      half4v hv;
#pragma unroll
      for (int reg = 0; reg < 4; reg++) {
        float v = fmaf(acc[m][j][reg], s, bb);
        hv[reg] = (_Float16)(istanh ? tanh_f(v) : sigm_f(v));
      }
      const int q = (wm * 4 + m) * 4 + quad;
      *(half4v*)(gb + (size_t)c * 512 + q * 16) = hv;
    }
  }
}

// -------- SRU recurrence over d; thread per (c, bx, q=4sp); pipelined ----
// gates block: [c][q][gate 4][spw 4] -> per d: 2 contiguous b128 loads.
__global__ __launch_bounds__(256) void recurrence_k(const _Float16* __restrict__ gates,
                                                    float* __restrict__ out) {
  const int idx = blockIdx.x * 256 + threadIdx.x;   // 64*72*32 = 147456
  const int q   = idx & 31;          // sp quad
  const int t2  = idx >> 5;          // c*72 + bx
  const int c   = t2 / NTILE;
  const int bx  = t2 - c * NTILE;
  const int hti = bx / 6, wti = bx - hti * 6;
  const int sp  = q * 4;
  const int h   = hti * 8 + (sp >> 4);
  const int w   = wti * 16 + (sp & 15);

  const _Float16* g0 = gates + (size_t)bx * GBLK + (size_t)c * 512 + q * 16;
  float* op = out + (size_t)c * DHW_ + (size_t)h * WW_ + w;

  // lo = {wx[0..3], f[0..3]}, hi = {r[0..3], x[0..3]}
#define LDLO(dv) (*(const half8*)(g0 + (size_t)(dv) * GDSTR))
#define LDHI(dv) (*(const half8*)(g0 + (size_t)(dv) * GDSTR + 8))

  // d = 0 (peeled): C = 1 - f
  half8 clo = LDLO(0), chi = LDHI(0);
  half8 nlo = LDLO(1), nhi = LDHI(1);
  float C[4];
  {
    float4 st;
#pragma unroll
    for (int k = 0; k < 4; k++) {
      C[k] = 1.f - (float)clo[4 + k];
      float r0 = (float)chi[k], x0 = (float)chi[4 + k];
      (&st.x)[k] = fmaf(r0, C[k] - x0, x0);
    }
    *(float4*)op = st;
  }
#pragma unroll 1
  for (int d = 1; d < DD_; d++) {
    clo = nlo; chi = nhi;
    if (d < DD_ - 1) {                 // prefetch d+1 while computing d
      nlo = LDLO(d + 1); nhi = LDHI(d + 1);
    }
    float4 st;
#pragma unroll
    for (int k = 0; k < 4; k++) {
      float wx0 = (float)clo[k],     f0 = (float)clo[4 + k];
      float r0  = (float)chi[k],     x0 = (float)chi[4 + k];
      C[k] = fmaf(f0, C[k] - wx0, wx0);
      (&st.x)[k] = fmaf(r0, C[k] - x0, x0);
    }
    *(float4*)(op + (size_t)d * HW_) = st;
  }
#undef LDLO
#undef LDHI
}

extern "C" void kernel_launch(void* const* d_in, const int* in_sizes, int n_in,
                              void* d_out, int out_size, void* d_ws, size_t ws_size,
                              hipStream_t stream) {
  const float* x     = (const float*)d_in[0];
  const float* w     = (const float*)d_in[1];
  const float* gamma = (const float*)d_in[2];
  const float* beta  = (const float*)d_in[3];
  const float* mean  = (const float*)d_in[4];
  const float* var   = (const float*)d_in[5];
  float* out = (float*)d_out;

  // ws: [wr2: 884736 B][xt: 8*316932*16 = 40567296 B][gates: 2232*65536 B]
  _Float16* wr2   = (_Float16*)d_ws;
  _Float16* xt    = (_Float16*)((char*)d_ws + 884736);
  _Float16* gates = (_Float16*)((char*)d_ws + 884736 + 40567296);

  prep_k<<<PREP_NB, 256, 0, stream>>>(w, x, wr2, xt);
  conv_mfma_k<<<NBLK, 512, 0, stream>>>(xt, wr2, gamma, beta, mean, var, gates);
  recurrence_k<<<(64 * NTILE * 32) / 256, 256, 0, stream>>>(gates, out);
}

// Round 8
// 406.843 us; speedup vs baseline: 1.0393x; 1.0142x over previous
//
#include <hip/hip_runtime.h>
#include <cstddef>

// Problem dims
#define CI_  64
#define CO_  256
#define DD_  31
#define HH_  96
#define WW_  96
#define HW_  (HH_*WW_)      // 9216
#define DHW_ (DD_*HW_)      // 285696
#define EPSV 1e-5f

// Padded channels-last fp16 input: xt[cig8][pd33][ph98][pw98][ci8]
#define PD_   33
#define PH_   98
#define PW_   98
#define PHW_  9604          // 98*98
#define PDHW_ 316932        // 33*9604

// Conv tile: M=128 (8h x 16w) x N=256, one d per block. 8 waves: 2 (M) x 4 (N).
// LDS halo: [dd3][row10][cig8][col18][ci8] halves — linear in task order.
#define S_COL 8
#define S_CIG 144           // 18*8
#define S_ROW 1152          // 8*144
#define S_DD  11520         // 10*1152
#define NTASK 4320          // 3*10*8*18 real 16B tasks
#define NTASKP 4352         // padded
#define XH_N  (NTASKP*8)    // 34816 halves = 69632 B

#define NTILE 72            // 12 hti * 6 wti per d-plane
#define NBLK  (NTILE*DD_)   // 2232 conv blocks (= 8*279, XCD-exact)

// gates layout: per (d,bx) block of 32768 halves: [c 64][sp 128][gate 4]
// -> recurrence reads ONE 8B half4 {wx,f,r,x} per (c,sp,d).
#define GBLK 32768
#define GDSTR ((size_t)NTILE * GBLK)

// prep kernel block ranges
#define PREP_RB 216         // repack: 55296 threads
#define PREP_PB 1239        // pad_zero: 316932 threads
#define PREP_TB 279         // transpose: 71424 threads
#define PREP_NB (PREP_RB + PREP_PB + PREP_TB)

typedef _Float16 half8   __attribute__((ext_vector_type(8)));
typedef _Float16 half4v  __attribute__((ext_vector_type(4)));
typedef float    float4v __attribute__((ext_vector_type(4)));

__device__ __forceinline__ void gl_lds16(const _Float16* g, _Float16* l) {
  __builtin_amdgcn_global_load_lds(
      (const __attribute__((address_space(1))) unsigned int*)(g),
      (__attribute__((address_space(3))) unsigned int*)(l), 16, 0, 0);
}

// -------- fused prep: weight repack + border zero + interior transpose --------
__global__ __launch_bounds__(256) void prep_k(const float* __restrict__ w,
                                              const float* __restrict__ x,
                                              _Float16* __restrict__ wr2,
                                              _Float16* __restrict__ xt) {
  const int bid = blockIdx.x;
  if (bid < PREP_RB) {
    int idx = bid * 256 + threadIdx.x;          // 27*2*16*4*16 = 55296
    int lw   = idx & 15;
    int quad = (idx >> 4) & 3;
    int cog  = (idx >> 6) & 15;
    int tkc  = idx >> 10;          // t*2+kc
    int kc   = tkc & 1;
    int t    = tkc >> 1;
    int co   = cog * 16 + lw;
    int cib  = kc * 32 + quad * 8;
    half8 v;
#pragma unroll
    for (int s = 0; s < 8; s++)
      v[s] = (_Float16)w[(size_t)co * 1728 + (size_t)(cib + s) * 27 + t];
    *(half8*)(wr2 + (size_t)idx * 8) = v;
  } else if (bid < PREP_RB + PREP_PB) {
    int p = (bid - PREP_RB) * 256 + threadIdx.x;
    if (p >= PDHW_) return;
    int pd  = p / PHW_;
    int rem = p - pd * PHW_;
    int ph  = rem / PW_;
    int pw  = rem - ph * PW_;
    bool in = (pd >= 1) & (pd <= DD_) & (ph >= 1) & (ph <= HH_) & (pw >= 1) & (pw <= WW_);
    if (in) return;
    half8 z = (half8)(_Float16)0.f;
#pragma unroll
    for (int cig = 0; cig < 8; cig++)
      *(half8*)(xt + ((size_t)cig * PDHW_ + p) * 8) = z;
  } else {
    int idx = (bid - PREP_RB - PREP_PB) * 256 + threadIdx.x;  // 31*96*24 = 71424
    if (idx >= 31 * 96 * 24) return;
    int wq  = idx % 24;
    int rem = idx / 24;
    int h   = rem % 96;
    int d   = rem / 96;
    const float* xp = x + (size_t)d * HW_ + (size_t)h * WW_ + wq * 4;
    size_t p0 = (size_t)(d + 1) * PHW_ + (size_t)(h + 1) * PW_ + (wq * 4 + 1);
#pragma unroll 1
    for (int cig = 0; cig < 8; cig++) {
      float4 vv[8];
#pragma unroll
      for (int s = 0; s < 8; s++)
        vv[s] = *(const float4*)(xp + (size_t)(cig * 8 + s) * DHW_);
#pragma unroll
      for (int k = 0; k < 4; k++) {
        half8 o;
#pragma unroll
        for (int s = 0; s < 8; s++) o[s] = (_Float16)(&vv[s].x)[k];
        *(half8*)(xt + ((size_t)cig * PDHW_ + p0 + k) * 8) = o;
      }
    }
  }
}

__device__ __forceinline__ float tanh_f(float v) {
  float t = __expf(-2.f * fabsf(v));
  return copysignf((1.f - t) * __builtin_amdgcn_rcpf(1.f + t), v);
}
__device__ __forceinline__ float sigm_f(float v) {
  return __builtin_amdgcn_rcpf(1.f + __expf(-v));
}

// -------- conv3d (implicit GEMM, f16 MFMA) + BN + act -> packed gates ----
// grid: 2232 blocks (XCD-chunk swizzled). block 512 = 8 waves (2 M x 4 N).
// K loop: 18 groups (kd x kc x kw), kh-row-sharing (6 ds_read feed 48 MFMA).
// Epilogue: XOR-swizzled LDS restage (dead halo buffer) packs the 4 gate
// values of each (c,sp) adjacently -> [c][sp][g4] global layout, stores
// 1KB-contiguous per wave.
__global__ __launch_bounds__(512, 4) void conv_mfma_k(
    const _Float16* __restrict__ xt, const _Float16* __restrict__ wr2,
    const float* __restrict__ gamma, const float* __restrict__ beta,
    const float* __restrict__ mean, const float* __restrict__ var,
    _Float16* __restrict__ gates)
{
  __shared__ _Float16 xh[XH_N];

  // XCD-chunked swizzle: 2232 = 8 * 279 exactly (bijective)
  const int bid  = blockIdx.x;
  const int flat = (bid & 7) * 279 + (bid >> 3);
  const int d    = flat / NTILE;
  const int bx   = flat - d * NTILE;
  const int wti  = bx % 6;
  const int hti  = bx / 6;
  const int h0   = hti * 8, w0 = wti * 16;

  const int tid  = threadIdx.x;
  const int lane = tid & 63;
  const int wave = __builtin_amdgcn_readfirstlane(tid >> 6);
  const int wm   = wave >> 2;        // M half (0,1)
  const int wn   = wave & 3;         // co group (64 each)
  const int lw   = lane & 15;        // A: m(spatial w)  B: n(co)
  const int quad = lane >> 4;        // k-group (8 ci)

  // ---- stage halo: 4352 16B tasks, direct global->LDS DMA, all in-bounds ----
#pragma unroll 1
  for (int it = 0; it < 9; ++it) {
    const int wb = it * 512 + wave * 64;       // wave-uniform LDS base task
    if (wb < NTASKP) {
      const int task = wb + lane;
      const int tt   = task < NTASK ? task : (NTASK - 1);  // spare lanes dup
      int col = tt % 18;
      int rc  = tt / 18;
      int cig = rc & 7;
      int dr  = rc >> 3;
      int dd  = dr / 10;
      int row = dr - dd * 10;
      const _Float16* g = xt + (((size_t)cig * PDHW_ + (size_t)(d + dd) * PHW_ +
                                 (size_t)(h0 + row) * PW_ + (w0 + col)) << 3);
      gl_lds16(g, xh + (size_t)wb * 8);
    }
  }

  float4v acc[4][4];
#pragma unroll
  for (int m = 0; m < 4; m++)
#pragma unroll
    for (int j = 0; j < 4; j++) acc[m][j] = (float4v)0.f;

  __syncthreads();   // vmcnt(0) drain of global_load_lds + barrier

  // ---- K loop: 18 groups, kh-row-sharing, fully unrolled ----
  const int abase0 = quad * S_CIG + lw * S_COL + (wm * 4) * S_ROW;
  half8 af[6];
  half8 bf[4];
#pragma unroll
  for (int kd = 0; kd < 3; ++kd) {
#pragma unroll
    for (int kc = 0; kc < 2; ++kc) {
#pragma unroll
      for (int kw = 0; kw < 3; ++kw) {
        const int ab = abase0 + kd * S_DD + kc * (4 * S_CIG) + kw * S_COL;
#pragma unroll
        for (int r = 0; r < 6; ++r)
          af[r] = *(const half8*)(xh + ab + r * S_ROW);
#pragma unroll
        for (int kh = 0; kh < 3; ++kh) {
          const int t = (kd * 3 + kh) * 3 + kw;
          const _Float16* bp =
              wr2 + (((size_t)((t * 2 + kc) * 16 + wn * 4)) << 9) + (lane << 3);
#pragma unroll
          for (int j = 0; j < 4; ++j)
            bf[j] = *(const half8*)(bp + ((size_t)j << 9));
          __builtin_amdgcn_s_setprio(1);
#pragma unroll
          for (int j = 0; j < 4; ++j) {
            acc[0][j] = __builtin_amdgcn_mfma_f32_16x16x32_f16(af[kh    ], bf[j], acc[0][j], 0, 0, 0);
            acc[1][j] = __builtin_amdgcn_mfma_f32_16x16x32_f16(af[kh + 1], bf[j], acc[1][j], 0, 0, 0);
            acc[2][j] = __builtin_amdgcn_mfma_f32_16x16x32_f16(af[kh + 2], bf[j], acc[2][j], 0, 0, 0);
            acc[3][j] = __builtin_amdgcn_mfma_f32_16x16x32_f16(af[kh + 3], bf[j], acc[3][j], 0, 0, 0);
          }
          __builtin_amdgcn_s_setprio(0);
        }
      }
    }
  }

  // ---- epilogue: BN + act -> swizzled LDS restage -> packed [c][sp][g4] ----
  __syncthreads();   // all A-reads done; halo LDS is dead, reuse as 64KB tile

  // LDS tile bytes: c*1024 + ((sp*8 + wn*2) ^ ((c&7)<<4))  (bijective per c)
  const bool istanh = (wn == 0) || (wn == 3);
#pragma unroll
  for (int j = 0; j < 4; j++) {
    const int co = wn * 64 + j * 16 + lw;
    const int c  = j * 16 + lw;
    const float s  = gamma[co] * rsqrtf(var[co] + EPSV);
    const float bb = fmaf(-mean[co], s, beta[co]);
    const int cbase = c << 10;
    const int key   = (c & 7) << 4;
#pragma unroll
    for (int m = 0; m < 4; m++) {
#pragma unroll
      for (int reg = 0; reg < 4; reg++) {
        float v = fmaf(acc[m][j][reg], s, bb);
        _Float16 a = (_Float16)(istanh ? tanh_f(v) : sigm_f(v));
        const int sp = wm * 64 + m * 16 + quad * 4 + reg;
        *(_Float16*)((char*)xh + cbase + (((sp << 3) + (wn << 1)) ^ key)) = a;
      }
    }
  }
  __syncthreads();

  // coalesced read-out: 8 rounds, c = wave*8+r, sp-pair = lane -> 16B each
  _Float16* gb = gates + (size_t)(d * NTILE + bx) * GBLK;
#pragma unroll
  for (int r = 0; r < 8; r++) {
    const int c = wave * 8 + r;
    const half8 rv = *(const half8*)((const char*)xh + (c << 10) +
                                     ((lane ^ (c & 7)) << 4));
    *(half8*)(gb + (size_t)c * 512 + lane * 8) = rv;   // 1KB contiguous/wave
  }
}

// -------- SRU recurrence over d; ONE thread per (c, bx, sp); 4-deep ring ----
// gates: [c][sp][g4] -> per d a single 8B half4 {wx,f,r,x}; loads independent.
__global__ __launch_bounds__(256) void recurrence_k(const _Float16* __restrict__ gates,
                                                    float* __restrict__ out) {
  const int idx = blockIdx.x * 256 + threadIdx.x;   // 64*72*128 = 589824
  const int sp  = idx & 127;
  const int t2  = idx >> 7;          // c*72 + bx
  const int c   = t2 / NTILE;
  const int bx  = t2 - c * NTILE;
  const int hti = bx / 6, wti = bx - hti * 6;
  const int h   = hti * 8 + (sp >> 4);
  const int w   = wti * 16 + (sp & 15);

  const _Float16* g0 = gates + (size_t)bx * GBLK + (size_t)c * 512 + sp * 4;
  float* op = out + (size_t)c * DHW_ + (size_t)h * WW_ + w;

#define LD(dv) (*(const half4v*)(g0 + (size_t)(dv) * GDSTR))
  half4v p[4];
#pragma unroll
  for (int i = 0; i < 4; i++) p[i] = LD(i);

  float C = 0.f;
#pragma unroll
  for (int d = 0; d < DD_; d++) {       // fully unrolled: p[d&3] is static
    half4v cur = p[d & 3];
    if (d + 4 < DD_) p[d & 3] = LD(d + 4);
    float wx = (float)cur[0], f = (float)cur[1];
    float r  = (float)cur[2], x = (float)cur[3];
    C = (d == 0) ? (1.f - f) : fmaf(f, C - wx, wx);
    op[(size_t)d * HW_] = fmaf(r, C - x, x);
  }
#undef LD
}

extern "C" void kernel_launch(void* const* d_in, const int* in_sizes, int n_in,
                              void* d_out, int out_size, void* d_ws, size_t ws_size,
                              hipStream_t stream) {
  const float* x     = (const float*)d_in[0];
  const float* w     = (const float*)d_in[1];
  const float* gamma = (const float*)d_in[2];
  const float* beta  = (const float*)d_in[3];
  const float* mean  = (const float*)d_in[4];
  const float* var   = (const float*)d_in[5];
  float* out = (float*)d_out;

  // ws: [wr2: 884736 B][xt: 8*316932*16 = 40567296 B][gates: 2232*65536 B]
  _Float16* wr2   = (_Float16*)d_ws;
  _Float16* xt    = (_Float16*)((char*)d_ws + 884736);
  _Float16* gates = (_Float16*)((char*)d_ws + 884736 + 40567296);

  prep_k<<<PREP_NB, 256, 0, stream>>>(w, x, wr2, xt);
  conv_mfma_k<<<NBLK, 512, 0, stream>>>(xt, wr2, gamma, beta, mean, var, gates);
  recurrence_k<<<(64 * NTILE * 128) / 256, 256, 0, stream>>>(gates, out);
}